// Round 6
// baseline (81.419 us; speedup 1.0000x reference)
//
#include <hip/hip_runtime.h>
#include <hip/hip_bf16.h>

#define HW    3136
#define HH    56
#define NCIN  256
#define KK    49
#define PH    68
#define PP    (PH*PH)   // 4624

// ---------------- ws layout (in floats) ----------------
#define OFF_WT    0          // [256][96] transposed concat conv weights
#define OFF_BCAT  24576      // [96]
#define OFF_TAB   24672      // [50][16][12] {s,sh,w0..7,pad,pad} per (unit,r)
#define OFF_WTAB  34272      // [8][49][12]  {b,w0..7,pad,pad,pad}
#define OFF_B2F   38976      // [8]
#define OFF_X1    39040      // [8][16][3136]
#define OFF_X2P   440448     // [8][16][4624]  reflect2+zero4 padded
#define OFF_X3P   1032320    // [8][64][4624]  reflect6 padded
#define OFF_TB    3399808    // [8][8][3136]

// ---------------- precompute tables ----------------
__global__ __launch_bounds__(256) void kprep(
    const float* __restrict__ w1, const float* __restrict__ b1,
    const float* __restrict__ w2, const float* __restrict__ b2,
    const float* __restrict__ w3, const float* __restrict__ b3,
    const float* __restrict__ bn1g, const float* __restrict__ bn1b,
    const float* __restrict__ bn1m, const float* __restrict__ bn1v,
    const float* __restrict__ wcw1,
    const float* __restrict__ bn2g, const float* __restrict__ bn2b,
    const float* __restrict__ bn2m, const float* __restrict__ bn2v,
    const float* __restrict__ wcw2, const float* __restrict__ bcw2,
    float* __restrict__ ws)
{
    int idx = blockIdx.x * 256 + threadIdx.x;
    if (idx < 24576) {                    // wT[c][o] = W[o][c]
        int o = idx >> 8, c = idx & 255;
        float v = (o < 16) ? w1[o * 256 + c]
                : (o < 32) ? w2[(o - 16) * 256 + c]
                           : w3[(o - 32) * 256 + c];
        ws[OFF_WT + c * 96 + o] = v;
    }
    int i2 = idx - 24576;                 // bcat [96]
    if (i2 >= 0 && i2 < 96) {
        float v = (i2 < 16) ? b1[i2] : (i2 < 32) ? b2[i2 - 16] : b3[i2 - 32];
        ws[OFF_BCAT + i2] = v;
    }
    int i3 = idx - 24672;                 // tab [50][16][12]
    if (i3 >= 0 && i3 < 9600) {
        int row = i3 / 12, c = i3 - row * 12;
        int uu = row >> 4, r = row & 15;
        int j = (uu < 49) ? (16 + r * KK + uu) : r;
        float val = 0.f;
        if (c == 0) {
            val = bn1g[j] / sqrtf(bn1v[j] + 1e-5f);
        } else if (c == 1) {
            float s = bn1g[j] / sqrtf(bn1v[j] + 1e-5f);
            val = bn1b[j] - bn1m[j] * s;
        } else if (c < 10) {
            int e = c - 2;
            float s2 = bn2g[e] / sqrtf(bn2v[e] + 1e-5f);
            val = wcw1[e * 800 + j] * s2;
        }
        ws[OFF_TAB + i3] = val;
    }
    int i4 = idx - 34272;                 // wtab [8][49][12]
    if (i4 >= 0 && i4 < 4704) {
        int row = i4 / 12, c = i4 - row * 12;   // row = g*49+k
        float val = 0.f;
        if (c == 0)      val = bcw2[row];
        else if (c < 9)  val = wcw2[row * 8 + (c - 1)];
        ws[OFF_WTAB + i4] = val;
    }
    int i5 = idx - 38976;                 // b2f [8]
    if (i5 >= 0 && i5 < 8) {
        float s2 = bn2g[i5] / sqrtf(bn2v[i5] + 1e-5f);
        ws[OFF_B2F + i5] = bn2b[i5] - bn2m[i5] * s2;
    }
}

// ---------------- fused 1x1 convs -> x1 / x2pad / x3pad ----------------
// 512 thr = 8 waves; block = 64 px; wave w owns out-ch [12w,12w+12).
// Also zeroes this block's share of the x2pad border band.
__global__ __launch_bounds__(512) void kconv(
    const float* __restrict__ x, const float* __restrict__ wT,
    const float* __restrict__ bcat, float* __restrict__ x1out,
    float* __restrict__ x2pad, float* __restrict__ x3pad)
{
    __shared__ float xl[64][64];
    const int tid = threadIdx.x;
    const int l   = tid & 63;
    const int wv  = __builtin_amdgcn_readfirstlane(tid >> 6);
    const int b   = blockIdx.x / 49;
    const int hw0 = (blockIdx.x % 49) * 64;
    const int ob  = wv * 12;

    // ---- zero x2pad border band (disjoint from conv-written region) ----
    {
        int z = (blockIdx.x % 49) * 336 + tid;
        if (tid < 336 && z < 16384) {
            int ch = z >> 10, cell = z & 1023;
            int p, q;
            if (cell < 272)      { p = cell / 68;          q = cell - p * 68; }
            else if (cell < 544) { int cc = cell - 272; p = 64 + cc / 68; q = cc - (p - 64) * 68; }
            else                 { int cc = cell - 544; p = 4 + (cc >> 3); int qq = cc & 7; q = (qq < 4) ? qq : 60 + qq; }
            x2pad[((size_t)b * 16 + ch) * PP + p * PH + q] = 0.f;
        }
    }

    float acc[12];
    const float* bc = bcat + ob;
#pragma unroll
    for (int i = 0; i < 12; ++i) acc[i] = bc[i];

    const float* xb = x + (size_t)b * NCIN * HW + hw0;

    for (int cc = 0; cc < 4; ++cc) {
        __syncthreads();
#pragma unroll
        for (int i = 0; i < 8; ++i)
            xl[i * 8 + wv][l] = xb[(size_t)(cc * 64 + i * 8 + wv) * HW + l];
        __syncthreads();

        const float* wp = wT + (cc * 64) * 96 + ob;
#pragma unroll 4
        for (int k = 0; k < 64; ++k) {
            float xv = xl[k][l];
            const float4* wq = (const float4*)(wp + k * 96);
            float4 A = wq[0], B = wq[1], C = wq[2];
            acc[0]  = fmaf(xv, A.x, acc[0]);  acc[1]  = fmaf(xv, A.y, acc[1]);
            acc[2]  = fmaf(xv, A.z, acc[2]);  acc[3]  = fmaf(xv, A.w, acc[3]);
            acc[4]  = fmaf(xv, B.x, acc[4]);  acc[5]  = fmaf(xv, B.y, acc[5]);
            acc[6]  = fmaf(xv, B.z, acc[6]);  acc[7]  = fmaf(xv, B.w, acc[7]);
            acc[8]  = fmaf(xv, C.x, acc[8]);  acc[9]  = fmaf(xv, C.y, acc[9]);
            acc[10] = fmaf(xv, C.z, acc[10]); acc[11] = fmaf(xv, C.w, acc[11]);
        }
    }

    // ---- stores with padded-buffer mirrors ----
    const int n  = hw0 + l;
    const int y  = n / HH;
    const int xx = n - y * HH;
    const int p0 = y + 6, q0 = xx + 6;
    const int yr3 = (y >= 1 && y <= 6) ? 6 - y : ((y >= 49 && y <= 54) ? 116 - y : -1);
    const int xr3 = (xx >= 1 && xx <= 6) ? 6 - xx : ((xx >= 49 && xx <= 54) ? 116 - xx : -1);
    const int yr2 = (y == 1 || y == 2) ? 6 - y : ((y == 53 || y == 54) ? 116 - y : -1);
    const int xr2 = (xx == 1 || xx == 2) ? 6 - xx : ((xx == 53 || xx == 54) ? 116 - xx : -1);

#pragma unroll
    for (int i = 0; i < 12; ++i) {
        const int ch = ob + i;             // wave-uniform
        const float v = acc[i];
        if (ch < 16) {
            x1out[((size_t)b * 16 + ch) * HW + n] = v;
        } else if (ch < 32) {
            float* pl = x2pad + ((size_t)b * 16 + (ch - 16)) * PP;
            pl[p0 * PH + q0] = v;
            if (yr2 >= 0)              pl[yr2 * PH + q0]  = v;
            if (xr2 >= 0)              pl[p0 * PH + xr2]  = v;
            if (yr2 >= 0 && xr2 >= 0)  pl[yr2 * PH + xr2] = v;
        } else {
            float* pl = x3pad + ((size_t)b * 64 + (ch - 32)) * PP;
            pl[p0 * PH + q0] = v;
            if (yr3 >= 0)              pl[yr3 * PH + q0]  = v;
            if (xr3 >= 0)              pl[p0 * PH + xr3]  = v;
            if (yr3 >= 0 && xr3 >= 0)  pl[yr3 * PH + xr3] = v;
        }
    }
}

// ---------------- t: per-pixel 8-dim bottleneck ----------------
// 1024 thr = 16 waves; block = 64 px; wave = tap-slice (16-way split).
__global__ __launch_bounds__(1024, 8) void kt(
    const float* __restrict__ x1, const float* __restrict__ x2pad,
    const float* __restrict__ tab, const float* __restrict__ b2f,
    float* __restrict__ tbuf)
{
    __shared__ float red[16][8][64];   // 32KB
    const int tid = threadIdx.x;
    const int w   = __builtin_amdgcn_readfirstlane(tid >> 6);
    const int l   = tid & 63;
    const int b   = blockIdx.x / 49;
    const int nb  = (blockIdx.x % 49) * 64;
    const int n   = nb + l;
    const int y   = n / HH;
    const int xx  = n - y * HH;
    const int pbase = y * PH + xx;

    const float* x1b = x1 + (size_t)b * 16 * HW + n;
    const float* x2b = x2pad + (size_t)b * 16 * PP + pbase;

    float acc[8];
#pragma unroll
    for (int g = 0; g < 8; ++g) acc[g] = 0.f;

    const int u0 = (50 * w) >> 4;
    const int u1 = (50 * (w + 1)) >> 4;

#pragma unroll 1
    for (int u = u0; u < u1; ++u) {
        const float* trow;
        const float* xp;
        size_t xstr;
        if (u == 0) {                       // wave-uniform branch (slice 0)
            trow = tab + 49 * 192;
            xp   = x1b;
            xstr = HW;
        } else {
            const int kk = u - 1;
            const int i  = kk / 7;
            const int jj = kk - i * 7;
            trow = tab + kk * 192;
            xp   = x2b + i * (2 * PH) + jj * 2;
            xstr = PP;
        }
#pragma unroll
        for (int r = 0; r < 16; ++r) {
            const float4* tq = (const float4*)(trow + r * 12);
            float4 A = tq[0], Bv = tq[1], Cv = tq[2];   // {s,sh,w0,w1},{w2..5},{w6,w7,-,-}
            float v = xp[(size_t)r * xstr];
            v = fmaxf(fmaf(v, A.x, A.y), 0.f);
            acc[0] = fmaf(v, A.z, acc[0]);  acc[1] = fmaf(v, A.w, acc[1]);
            acc[2] = fmaf(v, Bv.x, acc[2]); acc[3] = fmaf(v, Bv.y, acc[3]);
            acc[4] = fmaf(v, Bv.z, acc[4]); acc[5] = fmaf(v, Bv.w, acc[5]);
            acc[6] = fmaf(v, Cv.x, acc[6]); acc[7] = fmaf(v, Cv.y, acc[7]);
        }
    }

#pragma unroll
    for (int g = 0; g < 8; ++g) red[w][g][l] = acc[g];
    __syncthreads();

    if (tid < 512) {
        const int g  = tid >> 6;
        const int px = tid & 63;
        float s = b2f[g];
#pragma unroll
        for (int sl = 0; sl < 16; ++sl) s += red[sl][g][px];
        tbuf[((size_t)b * 8 + g) * HW + nb + px] = fmaxf(s, 0.f);
    }
}

// ---------------- aggregation: k-split over 16 waves ----------------
// 1024 thr = 16 waves = (g 0..7) x (kh 0..1); lane = px (64/block).
__global__ __launch_bounds__(1024, 8) void kagg(
    const float* __restrict__ x3pad, const float* __restrict__ tbuf,
    const float* __restrict__ wtab, float* __restrict__ out)
{
    __shared__ float red[8][8][64];    // 16KB
    const int tid  = threadIdx.x;
    const int wave = tid >> 6;
    const int g    = __builtin_amdgcn_readfirstlane(wave & 7);
    const int kh   = __builtin_amdgcn_readfirstlane(wave >> 3);
    const int l    = tid & 63;
    const int b    = blockIdx.x / 49;
    const int nb   = (blockIdx.x % 49) * 64;
    const int n    = nb + l;
    const int y    = n / HH;
    const int xx   = n - y * HH;
    const int pbase = y * PH + xx;

    float t[8];
#pragma unroll
    for (int e = 0; e < 8; ++e) t[e] = tbuf[((size_t)b * 8 + e) * HW + n];

    float acc[8];
#pragma unroll
    for (int s = 0; s < 8; ++s) acc[s] = 0.f;

    const float* x3b = x3pad + ((size_t)b * 64 + g * 8) * PP + pbase;
    const float* wg  = wtab + (size_t)g * KK * 12;

    const int k0 = kh * 25;
    const int k1 = kh ? KK : 25;

#pragma unroll 1
    for (int k = k0; k < k1; ++k) {
        const int i  = k / 7;
        const int jj = k - i * 7;
        const float* wrow = wg + k * 12;
        const float4* wq = (const float4*)wrow;
        float4 A = wq[0], Bv = wq[1];          // {b,w0,w1,w2},{w3..w6}
        float w7 = wrow[8];
        float wv = A.x;
        wv = fmaf(t[0], A.y, wv);  wv = fmaf(t[1], A.z, wv);
        wv = fmaf(t[2], A.w, wv);  wv = fmaf(t[3], Bv.x, wv);
        wv = fmaf(t[4], Bv.y, wv); wv = fmaf(t[5], Bv.z, wv);
        wv = fmaf(t[6], Bv.w, wv); wv = fmaf(t[7], w7, wv);

        const float* xp = x3b + i * (2 * PH) + jj * 2;
#pragma unroll
        for (int s = 0; s < 8; ++s)
            acc[s] = fmaf(xp[(size_t)s * PP], wv, acc[s]);
    }

    if (kh == 1) {
#pragma unroll
        for (int s = 0; s < 8; ++s) red[g][s][l] = acc[s];
    }
    __syncthreads();
    if (kh == 0) {
        float* op = out + ((size_t)b * 64 + g * 8) * HW + n;
#pragma unroll
        for (int s = 0; s < 8; ++s)
            op[(size_t)s * HW] = acc[s] + red[g][s][l];
    }
}

extern "C" void kernel_launch(void* const* d_in, const int* in_sizes, int n_in,
                              void* d_out, int out_size, void* d_ws, size_t ws_size,
                              hipStream_t stream) {
    const float* x    = (const float*)d_in[0];
    const float* w1   = (const float*)d_in[1];
    const float* b1   = (const float*)d_in[2];
    const float* w2   = (const float*)d_in[3];
    const float* b2   = (const float*)d_in[4];
    const float* w3   = (const float*)d_in[5];
    const float* b3   = (const float*)d_in[6];
    const float* bn1g = (const float*)d_in[7];
    const float* bn1b = (const float*)d_in[8];
    const float* bn1m = (const float*)d_in[9];
    const float* bn1v = (const float*)d_in[10];
    const float* wcw1 = (const float*)d_in[11];
    const float* bn2g = (const float*)d_in[12];
    const float* bn2b = (const float*)d_in[13];
    const float* bn2m = (const float*)d_in[14];
    const float* bn2v = (const float*)d_in[15];
    const float* wcw2 = (const float*)d_in[16];
    const float* bcw2 = (const float*)d_in[17];

    float* ws = (float*)d_ws;

    kprep<<<153, 256, 0, stream>>>(w1, b1, w2, b2, w3, b3,
                                   bn1g, bn1b, bn1m, bn1v, wcw1,
                                   bn2g, bn2b, bn2m, bn2v, wcw2, bcw2, ws);
    kconv<<<392, 512, 0, stream>>>(x, ws + OFF_WT, ws + OFF_BCAT,
                                   ws + OFF_X1, ws + OFF_X2P, ws + OFF_X3P);
    kt<<<392, 1024, 0, stream>>>(ws + OFF_X1, ws + OFF_X2P,
                                 ws + OFF_TAB, ws + OFF_B2F, ws + OFF_TB);
    kagg<<<392, 1024, 0, stream>>>(ws + OFF_X3P, ws + OFF_TB,
                                   ws + OFF_WTAB, (float*)d_out);
}

// Round 7
// 70.943 us; speedup vs baseline: 1.1477x; 1.1477x over previous
//
#include <hip/hip_runtime.h>
#include <hip/hip_bf16.h>

#define HW    3136
#define HH    56
#define NCIN  256
#define KK    49
#define PH    68
#define PP    (PH*PH)   // 4624

// ---------------- ws layout (in floats) ----------------
#define OFF_WT    0          // [256][96] transposed concat conv weights
#define OFF_BCAT  24576      // [96]
#define OFF_TAB   24672      // [50][16][12] {s,sh,w0..7,pad,pad} per (unit,r)
#define OFF_WTAB  34272      // [8][49][12]  {b,w0..7,pad,pad,pad}
#define OFF_B2F   38976      // [8]
#define OFF_X1    39040      // [8][16][3136]
#define OFF_X2P   440448     // [8][16][4624]  reflect2+zero4 padded
#define OFF_X3P   1032320    // [8][64][4624]  reflect6 padded

// ---------------- precompute tables ----------------
__global__ __launch_bounds__(256) void kprep(
    const float* __restrict__ w1, const float* __restrict__ b1,
    const float* __restrict__ w2, const float* __restrict__ b2,
    const float* __restrict__ w3, const float* __restrict__ b3,
    const float* __restrict__ bn1g, const float* __restrict__ bn1b,
    const float* __restrict__ bn1m, const float* __restrict__ bn1v,
    const float* __restrict__ wcw1,
    const float* __restrict__ bn2g, const float* __restrict__ bn2b,
    const float* __restrict__ bn2m, const float* __restrict__ bn2v,
    const float* __restrict__ wcw2, const float* __restrict__ bcw2,
    float* __restrict__ ws)
{
    int idx = blockIdx.x * 256 + threadIdx.x;
    if (idx < 24576) {                    // wT[c][o] = W[o][c]
        int o = idx >> 8, c = idx & 255;
        float v = (o < 16) ? w1[o * 256 + c]
                : (o < 32) ? w2[(o - 16) * 256 + c]
                           : w3[(o - 32) * 256 + c];
        ws[OFF_WT + c * 96 + o] = v;
    }
    int i2 = idx - 24576;                 // bcat [96]
    if (i2 >= 0 && i2 < 96) {
        float v = (i2 < 16) ? b1[i2] : (i2 < 32) ? b2[i2 - 16] : b3[i2 - 32];
        ws[OFF_BCAT + i2] = v;
    }
    int i3 = idx - 24672;                 // tab [50][16][12]
    if (i3 >= 0 && i3 < 9600) {
        int row = i3 / 12, c = i3 - row * 12;
        int uu = row >> 4, r = row & 15;
        int j = (uu < 49) ? (16 + r * KK + uu) : r;
        float val = 0.f;
        if (c == 0) {
            val = bn1g[j] / sqrtf(bn1v[j] + 1e-5f);
        } else if (c == 1) {
            float s = bn1g[j] / sqrtf(bn1v[j] + 1e-5f);
            val = bn1b[j] - bn1m[j] * s;
        } else if (c < 10) {
            int e = c - 2;
            float s2 = bn2g[e] / sqrtf(bn2v[e] + 1e-5f);
            val = wcw1[e * 800 + j] * s2;
        }
        ws[OFF_TAB + i3] = val;
    }
    int i4 = idx - 34272;                 // wtab [8][49][12]
    if (i4 >= 0 && i4 < 4704) {
        int row = i4 / 12, c = i4 - row * 12;   // row = g*49+k
        float val = 0.f;
        if (c == 0)      val = bcw2[row];
        else if (c < 9)  val = wcw2[row * 8 + (c - 1)];
        ws[OFF_WTAB + i4] = val;
    }
    int i5 = idx - 38976;                 // b2f [8]
    if (i5 >= 0 && i5 < 8) {
        float s2 = bn2g[i5] / sqrtf(bn2v[i5] + 1e-5f);
        ws[OFF_B2F + i5] = bn2b[i5] - bn2m[i5] * s2;
    }
}

// ---------------- fused 1x1 convs -> x1 / x2pad / x3pad ----------------
// 512 thr = 8 waves; block = 64 px; wave w owns out-ch [12w,12w+12).
// Also zeroes this block's share of the x2pad border band.
__global__ __launch_bounds__(512) void kconv(
    const float* __restrict__ x, const float* __restrict__ wT,
    const float* __restrict__ bcat, float* __restrict__ x1out,
    float* __restrict__ x2pad, float* __restrict__ x3pad)
{
    __shared__ float xl[64][64];
    const int tid = threadIdx.x;
    const int l   = tid & 63;
    const int wv  = __builtin_amdgcn_readfirstlane(tid >> 6);
    const int b   = blockIdx.x / 49;
    const int hw0 = (blockIdx.x % 49) * 64;
    const int ob  = wv * 12;

    // ---- zero x2pad border band (disjoint from conv-written region) ----
    {
        int z = (blockIdx.x % 49) * 336 + tid;
        if (tid < 336 && z < 16384) {
            int ch = z >> 10, cell = z & 1023;
            int p, q;
            if (cell < 272)      { p = cell / 68;          q = cell - p * 68; }
            else if (cell < 544) { int cc = cell - 272; p = 64 + cc / 68; q = cc - (p - 64) * 68; }
            else                 { int cc = cell - 544; p = 4 + (cc >> 3); int qq = cc & 7; q = (qq < 4) ? qq : 60 + qq; }
            x2pad[((size_t)b * 16 + ch) * PP + p * PH + q] = 0.f;
        }
    }

    float acc[12];
    const float* bc = bcat + ob;
#pragma unroll
    for (int i = 0; i < 12; ++i) acc[i] = bc[i];

    const float* xb = x + (size_t)b * NCIN * HW + hw0;

    for (int cc = 0; cc < 4; ++cc) {
        __syncthreads();
#pragma unroll
        for (int i = 0; i < 8; ++i)
            xl[i * 8 + wv][l] = xb[(size_t)(cc * 64 + i * 8 + wv) * HW + l];
        __syncthreads();

        const float* wp = wT + (cc * 64) * 96 + ob;
#pragma unroll 4
        for (int k = 0; k < 64; ++k) {
            float xv = xl[k][l];
            const float4* wq = (const float4*)(wp + k * 96);
            float4 A = wq[0], B = wq[1], C = wq[2];
            acc[0]  = fmaf(xv, A.x, acc[0]);  acc[1]  = fmaf(xv, A.y, acc[1]);
            acc[2]  = fmaf(xv, A.z, acc[2]);  acc[3]  = fmaf(xv, A.w, acc[3]);
            acc[4]  = fmaf(xv, B.x, acc[4]);  acc[5]  = fmaf(xv, B.y, acc[5]);
            acc[6]  = fmaf(xv, B.z, acc[6]);  acc[7]  = fmaf(xv, B.w, acc[7]);
            acc[8]  = fmaf(xv, C.x, acc[8]);  acc[9]  = fmaf(xv, C.y, acc[9]);
            acc[10] = fmaf(xv, C.z, acc[10]); acc[11] = fmaf(xv, C.w, acc[11]);
        }
    }

    // ---- stores with padded-buffer mirrors ----
    const int n  = hw0 + l;
    const int y  = n / HH;
    const int xx = n - y * HH;
    const int p0 = y + 6, q0 = xx + 6;
    const int yr3 = (y >= 1 && y <= 6) ? 6 - y : ((y >= 49 && y <= 54) ? 116 - y : -1);
    const int xr3 = (xx >= 1 && xx <= 6) ? 6 - xx : ((xx >= 49 && xx <= 54) ? 116 - xx : -1);
    const int yr2 = (y == 1 || y == 2) ? 6 - y : ((y == 53 || y == 54) ? 116 - y : -1);
    const int xr2 = (xx == 1 || xx == 2) ? 6 - xx : ((xx == 53 || xx == 54) ? 116 - xx : -1);

#pragma unroll
    for (int i = 0; i < 12; ++i) {
        const int ch = ob + i;             // wave-uniform
        const float v = acc[i];
        if (ch < 16) {
            x1out[((size_t)b * 16 + ch) * HW + n] = v;
        } else if (ch < 32) {
            float* pl = x2pad + ((size_t)b * 16 + (ch - 16)) * PP;
            pl[p0 * PH + q0] = v;
            if (yr2 >= 0)              pl[yr2 * PH + q0]  = v;
            if (xr2 >= 0)              pl[p0 * PH + xr2]  = v;
            if (yr2 >= 0 && xr2 >= 0)  pl[yr2 * PH + xr2] = v;
        } else {
            float* pl = x3pad + ((size_t)b * 64 + (ch - 32)) * PP;
            pl[p0 * PH + q0] = v;
            if (yr3 >= 0)              pl[yr3 * PH + q0]  = v;
            if (xr3 >= 0)              pl[p0 * PH + xr3]  = v;
            if (yr3 >= 0 && xr3 >= 0)  pl[yr3 * PH + xr3] = v;
        }
    }
}

// ---------------- fused t + aggregation ----------------
// 512 thr = 8 waves; block = 64 px.
// Phase 1 (round-5 kt): wave = tap-slice (8-way), t -> LDS tl.
// Phase 2 (round-5 kagg): wave = g; lane = (s-half, px-pair); float2 path.
__global__ __launch_bounds__(512) void kmainB(
    const float* __restrict__ x1, const float* __restrict__ x2pad,
    const float* __restrict__ x3pad, const float* __restrict__ tab,
    const float* __restrict__ b2f, const float* __restrict__ wtab,
    float* __restrict__ out)
{
    __shared__ float red[8][8][64];   // 16KB
    __shared__ float tl[8][64];       // 2KB
    const int tid = threadIdx.x;
    const int w   = __builtin_amdgcn_readfirstlane(tid >> 6);
    const int l   = tid & 63;
    const int b   = blockIdx.x / 49;
    const int nb  = (blockIdx.x % 49) * 64;
    const int n   = nb + l;
    const int y   = n / HH;
    const int xx  = n - y * HH;
    const int pbase = y * PH + xx;

    // ---- phase 1: t ----
    const float* x1b = x1 + (size_t)b * 16 * HW + n;
    const float* x2b = x2pad + (size_t)b * 16 * PP + pbase;

    float acc[8];
#pragma unroll
    for (int g = 0; g < 8; ++g) acc[g] = 0.f;

    const int u0 = (50 * w) >> 3;
    const int u1 = (50 * (w + 1)) >> 3;

#pragma unroll 1
    for (int u = u0; u < u1; ++u) {
        const float* trow;
        const float* xp;
        size_t xstr;
        if (u == 0) {                       // only wave 0 hits this (uniform)
            trow = tab + 49 * 192;
            xp   = x1b;
            xstr = HW;
        } else {
            const int kk = u - 1;
            const int i  = kk / 7;
            const int jj = kk - i * 7;
            trow = tab + kk * 192;
            xp   = x2b + i * (2 * PH) + jj * 2;
            xstr = PP;
        }
#pragma unroll
        for (int r = 0; r < 16; ++r) {
            const float4* tq = (const float4*)(trow + r * 12);
            float4 A = tq[0], Bv = tq[1], Cv = tq[2];   // {s,sh,w0,w1},{w2..5},{w6,w7,-,-}
            float v = xp[(size_t)r * xstr];
            v = fmaxf(fmaf(v, A.x, A.y), 0.f);
            acc[0] = fmaf(v, A.z, acc[0]);  acc[1] = fmaf(v, A.w, acc[1]);
            acc[2] = fmaf(v, Bv.x, acc[2]); acc[3] = fmaf(v, Bv.y, acc[3]);
            acc[4] = fmaf(v, Bv.z, acc[4]); acc[5] = fmaf(v, Bv.w, acc[5]);
            acc[6] = fmaf(v, Cv.x, acc[6]); acc[7] = fmaf(v, Cv.y, acc[7]);
        }
    }

#pragma unroll
    for (int g = 0; g < 8; ++g) red[w][g][l] = acc[g];
    __syncthreads();

    {   // 512 threads <-> (g, px); fold bn2 bias + relu
        const int g  = tid >> 6;
        const int px = tid & 63;
        float s = b2f[g];
#pragma unroll
        for (int ww = 0; ww < 8; ++ww) s += red[ww][g][px];
        tl[g][px] = fmaxf(s, 0.f);
    }
    __syncthreads();

    // ---- phase 2: aggregation (wave = g; lane = s-half x px-pair) ----
    const int g   = w;
    const int sh  = l >> 5;
    const int pp2 = l & 31;
    const int n0  = nb + pp2 * 2;          // even -> pair never straddles a row
    const int y0  = n0 / HH;
    const int xx0 = n0 - y0 * HH;
    const int pb2 = y0 * PH + xx0;

    float t0[8], t1[8];
#pragma unroll
    for (int e = 0; e < 8; ++e) {
        t0[e] = tl[e][pp2 * 2];
        t1[e] = tl[e][pp2 * 2 + 1];
    }

    float2 acc2[4];
#pragma unroll
    for (int s = 0; s < 4; ++s) acc2[s] = make_float2(0.f, 0.f);

    const float* x3b = x3pad + ((size_t)b * 64 + g * 8 + sh * 4) * PP + pb2;
    const float* wg  = wtab + (size_t)g * KK * 12;   // wave-uniform -> s_load

#pragma unroll 1
    for (int i = 0; i < 7; ++i) {
        const float* xrow = x3b + i * (2 * PH);
#pragma unroll
        for (int jj = 0; jj < 7; ++jj) {
            const int k = i * 7 + jj;
            const float* wrow = wg + k * 12;
            const float4* wq = (const float4*)wrow;
            float4 A = wq[0], Bv = wq[1];          // {b,w0,w1,w2},{w3..w6}
            float w7 = wrow[8];
            float w0 = A.x, w1 = A.x;
            w0 = fmaf(t0[0], A.y, w0);  w1 = fmaf(t1[0], A.y, w1);
            w0 = fmaf(t0[1], A.z, w0);  w1 = fmaf(t1[1], A.z, w1);
            w0 = fmaf(t0[2], A.w, w0);  w1 = fmaf(t1[2], A.w, w1);
            w0 = fmaf(t0[3], Bv.x, w0); w1 = fmaf(t1[3], Bv.x, w1);
            w0 = fmaf(t0[4], Bv.y, w0); w1 = fmaf(t1[4], Bv.y, w1);
            w0 = fmaf(t0[5], Bv.z, w0); w1 = fmaf(t1[5], Bv.z, w1);
            w0 = fmaf(t0[6], Bv.w, w0); w1 = fmaf(t1[6], Bv.w, w1);
            w0 = fmaf(t0[7], w7, w0);   w1 = fmaf(t1[7], w7, w1);
#pragma unroll
            for (int s = 0; s < 4; ++s) {
                float2 xv = *(const float2*)(xrow + (size_t)s * PP + jj * 2);
                acc2[s].x = fmaf(xv.x, w0, acc2[s].x);
                acc2[s].y = fmaf(xv.y, w1, acc2[s].y);
            }
        }
    }

    float* op = out + ((size_t)b * 64 + g * 8 + sh * 4) * HW + n0;
#pragma unroll
    for (int s = 0; s < 4; ++s)
        *(float2*)(op + (size_t)s * HW) = acc2[s];
}

extern "C" void kernel_launch(void* const* d_in, const int* in_sizes, int n_in,
                              void* d_out, int out_size, void* d_ws, size_t ws_size,
                              hipStream_t stream) {
    const float* x    = (const float*)d_in[0];
    const float* w1   = (const float*)d_in[1];
    const float* b1   = (const float*)d_in[2];
    const float* w2   = (const float*)d_in[3];
    const float* b2   = (const float*)d_in[4];
    const float* w3   = (const float*)d_in[5];
    const float* b3   = (const float*)d_in[6];
    const float* bn1g = (const float*)d_in[7];
    const float* bn1b = (const float*)d_in[8];
    const float* bn1m = (const float*)d_in[9];
    const float* bn1v = (const float*)d_in[10];
    const float* wcw1 = (const float*)d_in[11];
    const float* bn2g = (const float*)d_in[12];
    const float* bn2b = (const float*)d_in[13];
    const float* bn2m = (const float*)d_in[14];
    const float* bn2v = (const float*)d_in[15];
    const float* wcw2 = (const float*)d_in[16];
    const float* bcw2 = (const float*)d_in[17];

    float* ws = (float*)d_ws;

    kprep<<<153, 256, 0, stream>>>(w1, b1, w2, b2, w3, b3,
                                   bn1g, bn1b, bn1m, bn1v, wcw1,
                                   bn2g, bn2b, bn2m, bn2v, wcw2, bcw2, ws);
    kconv<<<392, 512, 0, stream>>>(x, ws + OFF_WT, ws + OFF_BCAT,
                                   ws + OFF_X1, ws + OFF_X2P, ws + OFF_X3P);
    kmainB<<<392, 512, 0, stream>>>(ws + OFF_X1, ws + OFF_X2P, ws + OFF_X3P,
                                    ws + OFF_TAB, ws + OFF_B2F, ws + OFF_WTAB,
                                    (float*)d_out);
}